// Round 10
// baseline (147.199 us; speedup 1.0000x reference)
//
#include <hip/hip_runtime.h>

#define NUM_JOINTS 24
#define NUM_VERTS  6890
#define NUM_COORDS (NUM_VERTS * 3)   // 20670
#define NUM_BETAS  10
#define KTOT       217               // 10 betas + 207 pose features
#define KPAD       224               // padded K for MFMA (7 x 32)
#define BATCH      512
#define VPAD       6912              // padded vertex count

// ---- ws layout (float offsets); ushort regions: floats = ushorts/2 ----
#define WS_SJP  0          //  85536: float 108 strips x 792 partials
#define WS_XBF  85536      //  57344: ushort 512 x 224
#define WS_DBF  142880     // 2322432: ushort 20736 x 224
#define WS_WHBF 2465312    // 110592: ushort 6912 x 32
#define WS_AH   2575904    // 131072: ushort 8192 x 32
#define WS_AL   2706976    // 131072: ushort 8192 x 32
#define WS_RS   2838048    // 110592: float Rs[512][24][9]  -> total ~11.8 MB

typedef __attribute__((ext_vector_type(8))) short short8;
typedef __attribute__((ext_vector_type(4))) float f32x4;

__device__ inline unsigned short f2bf(float f) {
    union { float f; unsigned u; } c; c.f = f;
    unsigned u = c.u;
    u += 0x7fffu + ((u >> 16) & 1u);   // RNE
    return (unsigned short)(u >> 16);
}
__device__ inline float bf2f(unsigned short h) {
    union { unsigned u; float f; } c; c.u = ((unsigned)h) << 16;
    return c.f;
}

struct PBShm {
    float Rs[4][24][9];
    float Jl[4][24][3];
    float Rg[4][24][9];
    float tg[4][24][3];
    float As[4][24][12];
};   // 13824 B

// ================= k_prep (r10): 507 blocks =================
// strips write plain partials (no atomics -> no memset dispatch);
// rodrigues + xbf blocks (t 459..506) as r9.
__global__ __launch_bounds__(256) void k_prep(const float* __restrict__ Jr,
                                              const float* __restrict__ sd,
                                              const float* __restrict__ pd,
                                              const float* __restrict__ vt,
                                              const float* __restrict__ w,
                                              const float* __restrict__ x,
                                              float* __restrict__ ws) {
    __shared__ __align__(16) unsigned char smem[28928];
    const int t   = blockIdx.x;
    const int tid = threadIdx.x;
    unsigned short* whbf = (unsigned short*)(ws + WS_WHBF);
    unsigned short* dbf  = (unsigned short*)(ws + WS_DBF);
    unsigned short* xbf  = (unsigned short*)(ws + WS_XBF);

    if (t < 27) {
        const int v = t * 256 + tid;      // < 6912
        const bool ok = (v < NUM_VERTS);
        unsigned short row[32];
        #pragma unroll
        for (int j = 0; j < 32; ++j)
            row[j] = f2bf((ok && j < 24) ? w[v * 24 + j] : 0.f);
        #pragma unroll
        for (int i = 0; i < 4; ++i)
            *(float4*)(whbf + (size_t)v * 32 + i * 8) = *(const float4*)(&row[i * 8]);
    } else if (t < 351) {
        unsigned* L = (unsigned*)smem;        // [64][113] dwords
        const int c0   = (t - 27) * 64;
        const int lane = tid & 63;
        const int grp  = tid >> 6;
        const int c    = c0 + lane;
        const bool cv  = (c < NUM_COORDS);
        #pragma unroll 4
        for (int i = 0; i < 28; ++i) {
            const int p  = i * 4 + grp;
            const int k0 = 2 * p, k1 = k0 + 1;
            float v0 = 0.f, v1 = 0.f;
            if (cv) {
                v0 = (k0 < 10) ? sd[(size_t)k0 * NUM_COORDS + c]
                   : (k0 < KTOT) ? pd[(size_t)(k0 - 10) * NUM_COORDS + c] : 0.f;
                v1 = (k1 < 10) ? sd[(size_t)k1 * NUM_COORDS + c]
                   : (k1 < KTOT) ? pd[(size_t)(k1 - 10) * NUM_COORDS + c] : 0.f;
            }
            L[lane * 113 + p] = (unsigned)f2bf(v0) | ((unsigned)f2bf(v1) << 16);
        }
        __syncthreads();
        #pragma unroll
        for (int i = 0; i < 7; ++i) {
            const int idx = i * 256 + tid;
            const int row = idx / 28;
            const int q   = idx % 28;
            uint4 val;
            val.x = L[row * 113 + q * 4 + 0];
            val.y = L[row * 113 + q * 4 + 1];
            val.z = L[row * 113 + q * 4 + 2];
            val.w = L[row * 113 + q * 4 + 3];
            *(uint4*)(dbf + (size_t)(c0 + row) * KPAD + q * 8) = val;
        }
    } else if (t < 459) {
        float* Jl = (float*)smem;
        float* S  = (float*)smem + 64 * 25;
        const int strip = t - 351;
        const int v0 = strip * 64;
        #pragma unroll
        for (int i = 0; i < 6; ++i) {
            const int idx = i * 256 + tid;
            const int v = idx / 24, j = idx % 24;
            Jl[v * 25 + j] = (v0 + v < NUM_VERTS) ? Jr[(size_t)(v0 + v) * 24 + j] : 0.f;
        }
        #pragma unroll
        for (int i = 0; i < 9; ++i) {
            const int idx = i * 256 + tid;
            if (idx < 33 * 64) {
                const int s = idx / 64, v = idx % 64;
                float val = 0.f;
                if (v0 + v < NUM_VERTS) {
                    if (s < 30) val = sd[(size_t)(s / 3) * NUM_COORDS + (size_t)(v0 + v) * 3 + (s % 3)];
                    else        val = vt[(size_t)(v0 + v) * 3 + (s - 30)];
                }
                S[s * 64 + v] = val;
            }
        }
        __syncthreads();
        float* wsp = ws + WS_SJP + (size_t)strip * 792;
        for (int o = tid; o < 792; o += 256) {
            const int s = o / 24, j = o % 24;
            float sum = 0.f;
            #pragma unroll 8
            for (int v = 0; v < 64; ++v)
                sum += S[s * 64 + v] * Jl[v * 25 + j];
            wsp[o] = sum;
        }
    } else {
        // rodrigues + xbf: thread = one (b, j) pair (r9-verified)
        const int idx = (t - 459) * 256 + tid;   // < 12288
        const int b = idx / 24;
        const int j = idx % 24;
        const float* row = x + b * (NUM_BETAS + 72);
        const float t0 = row[3 * j + 0], t1 = row[3 * j + 1], t2 = row[3 * j + 2];
        const float a0 = t0 + 1e-8f, a1 = t1 + 1e-8f, a2 = t2 + 1e-8f;
        const float angle = sqrtf(a0 * a0 + a1 * a1 + a2 * a2);
        const float inv = 1.0f / angle;
        const float rx = t0 * inv, ry = t1 * inv, rz = t2 * inv;
        const float c = cosf(angle), sn = sinf(angle), o = 1.f - c;
        float R[9];
        R[0] = c + o * rx * rx;       R[1] = o * rx * ry - sn * rz; R[2] = o * rx * rz + sn * ry;
        R[3] = o * rx * ry + sn * rz; R[4] = c + o * ry * ry;       R[5] = o * ry * rz - sn * rx;
        R[6] = o * rx * rz - sn * ry; R[7] = o * ry * rz + sn * rx; R[8] = c + o * rz * rz;
        float* rsd = ws + WS_RS + (size_t)(b * 24 + j) * 9;
        #pragma unroll
        for (int i = 0; i < 9; ++i) rsd[i] = R[i];
        if (j >= 1) {
            #pragma unroll
            for (int i = 0; i < 9; ++i) {
                const float pf = R[i] - ((i == 0 || i == 4 || i == 8) ? 1.f : 0.f);
                xbf[(size_t)b * KPAD + 10 + (j - 1) * 9 + i] = f2bf(pf);
            }
        } else {
            #pragma unroll
            for (int k = 0; k < NUM_BETAS; ++k)
                xbf[(size_t)b * KPAD + k] = f2bf(row[72 + k]);
            #pragma unroll
            for (int k = KTOT; k < KPAD; ++k)
                xbf[(size_t)b * KPAD + k] = 0;
        }
    }
}

// ================= k_pb (r10): 128 blocks x 4 batches =================
// Folds the SJ reduce in as a PARALLEL per-block pass: each thread owns ~3
// columns, 4-way-interleaved accumulators (reduction order identical to r8's
// k_red -> J bit-identical). One fewer dispatch than r8/r9.
__global__ __launch_bounds__(256) void k_pb(const float* __restrict__ x,
                                            float* __restrict__ ws) {
    __shared__ PBShm P;
    __shared__ float SJf[792];
    unsigned short* ahi = (unsigned short*)(ws + WS_AH);
    unsigned short* alo = (unsigned short*)(ws + WS_AL);
    const int tid = threadIdx.x;

    {
        const float* wsp = ws + WS_SJP;
        for (int o = tid; o < 792; o += 256) {
            float s0 = 0.f, s1 = 0.f, s2 = 0.f, s3 = 0.f;
            #pragma unroll
            for (int s = 0; s < 108; s += 4) {
                s0 += wsp[(size_t)(s + 0) * 792 + o];
                s1 += wsp[(size_t)(s + 1) * 792 + o];
                s2 += wsp[(size_t)(s + 2) * 792 + o];
                s3 += wsp[(size_t)(s + 3) * 792 + o];
            }
            SJf[o] = (s0 + s1) + (s2 + s3);
        }
    }
    __syncthreads();

    const int sub  = tid >> 6;
    const int lane = tid & 63;
    const int b = blockIdx.x * 4 + sub;
    const float* row = x + b * (NUM_BETAS + 72);

    if (lane < 24) {
        const int j = lane;
        const float* rsd = ws + WS_RS + (size_t)(b * 24 + j) * 9;
        #pragma unroll
        for (int i = 0; i < 9; ++i) P.Rs[sub][j][i] = rsd[i];
        #pragma unroll
        for (int c3 = 0; c3 < 3; ++c3) {
            float s = SJf[(30 + c3) * 24 + j];
            #pragma unroll
            for (int k = 0; k < NUM_BETAS; ++k)
                s += row[72 + k] * SJf[(k * 3 + c3) * 24 + j];
            P.Jl[sub][j][c3] = s;
        }
    }
    __syncthreads();

    // ---- parallel kinematic chain: lane j = joint j, tree levels (r8-verified) ----
    {
        constexpr int PAR[24] = {0, 0, 0, 0, 1, 2, 3, 4, 5, 6, 7, 8,
                                 9, 9, 9, 12, 13, 14, 16, 17, 18, 19, 20, 21};
        int p = 0;
        #pragma unroll
        for (int q = 1; q < 24; ++q) if (lane == q) p = PAR[q];

        if (lane == 0) {
            #pragma unroll
            for (int q = 0; q < 9; ++q) P.Rg[sub][0][q] = P.Rs[sub][0][q];
            #pragma unroll
            for (int c3 = 0; c3 < 3; ++c3) P.tg[sub][0][c3] = P.Jl[sub][0][c3];
        }
        __syncthreads();

        #pragma unroll
        for (int lvl = 1; lvl <= 8; ++lvl) {
            constexpr unsigned LVL[9] = {0x000001u, 0x00000Eu, 0x000070u,
                                         0x000380u, 0x007C00u, 0x038000u,
                                         0x0C0000u, 0x300000u, 0xC00000u};
            if (lane < 24 && ((LVL[lvl] >> lane) & 1u)) {
                const int j = lane;
                float Rp[9], Rsl[9], tp[3];
                #pragma unroll
                for (int q = 0; q < 9; ++q) { Rp[q] = P.Rg[sub][p][q]; Rsl[q] = P.Rs[sub][j][q]; }
                #pragma unroll
                for (int r = 0; r < 3; ++r) tp[r] = P.tg[sub][p][r];
                float tmp[9];
                #pragma unroll
                for (int r = 0; r < 3; ++r)
                    #pragma unroll
                    for (int cc = 0; cc < 3; ++cc)
                        tmp[r * 3 + cc] = Rp[r * 3 + 0] * Rsl[0 + cc] +
                                          Rp[r * 3 + 1] * Rsl[3 + cc] +
                                          Rp[r * 3 + 2] * Rsl[6 + cc];
                #pragma unroll
                for (int q = 0; q < 9; ++q) P.Rg[sub][j][q] = tmp[q];
                const float tr0 = P.Jl[sub][j][0] - P.Jl[sub][p][0];
                const float tr1 = P.Jl[sub][j][1] - P.Jl[sub][p][1];
                const float tr2 = P.Jl[sub][j][2] - P.Jl[sub][p][2];
                #pragma unroll
                for (int r = 0; r < 3; ++r)
                    P.tg[sub][j][r] = Rp[r * 3 + 0] * tr0 + Rp[r * 3 + 1] * tr1 +
                                      Rp[r * 3 + 2] * tr2 + tp[r];
            }
            __syncthreads();
        }
    }

    if (lane < 24) {
        const int j = lane;
        #pragma unroll
        for (int r = 0; r < 3; ++r) {
            const float tt = P.tg[sub][j][r] - (P.Rg[sub][j][r * 3 + 0] * P.Jl[sub][j][0] +
                                                P.Rg[sub][j][r * 3 + 1] * P.Jl[sub][j][1] +
                                                P.Rg[sub][j][r * 3 + 2] * P.Jl[sub][j][2]);
            P.As[sub][j][r * 4 + 0] = P.Rg[sub][j][r * 3 + 0];
            P.As[sub][j][r * 4 + 1] = P.Rg[sub][j][r * 3 + 1];
            P.As[sub][j][r * 4 + 2] = P.Rg[sub][j][r * 3 + 2];
            P.As[sub][j][r * 4 + 3] = tt;
        }
    }
    __syncthreads();

    if (lane < 32) {
        const int r = lane >> 1;
        const int half = lane & 1;
        unsigned short hi[16], lo[16];
        #pragma unroll
        for (int i = 0; i < 16; ++i) {
            const int j = half * 16 + i;
            float v = 0.f;
            if (r < 12 && j < 24) v = P.As[sub][j][r];
            const unsigned short h = f2bf(v);
            hi[i] = h;
            lo[i] = f2bf(v - bf2f(h));
        }
        unsigned short* dh = ahi + ((size_t)b * 16 + r) * 32 + half * 16;
        unsigned short* dl = alo + ((size_t)b * 16 + r) * 32 + half * 16;
        #pragma unroll
        for (int i = 0; i < 2; ++i) {
            *(float4*)(dh + i * 8) = *(const float4*)(&hi[i * 8]);
            *(float4*)(dl + i * 8) = *(const float4*)(&lo[i * 8]);
        }
    }
}

// ================= k_fused (r6/r8-verified): grid (108, 16), 4 blocks/CU =================
__global__ __launch_bounds__(256, 4) void k_fused(const float* __restrict__ vt,
                                                  float* __restrict__ out,
                                                  float* __restrict__ ws) {
    __shared__ __align__(16) float VP[32 * 194];     // 24832 B: v_posed[bb][cc]
    __shared__ __align__(16) float Tsf[4][32 * 20];  // 10240 B: half-T per wave

    const unsigned short* dbf  = (const unsigned short*)(ws + WS_DBF);
    const unsigned short* xbf  = (const unsigned short*)(ws + WS_XBF);
    const unsigned short* whbf = (const unsigned short*)(ws + WS_WHBF);
    const unsigned short* ahi  = (const unsigned short*)(ws + WS_AH);
    const unsigned short* alo  = (const unsigned short*)(ws + WS_AL);

    const int tid  = threadIdx.x;
    const int wave = tid >> 6;
    const int lane = tid & 63;
    const int col  = lane & 15;
    const int quad = lane >> 4;
    const int c0   = blockIdx.x * 192;
    const int b0   = blockIdx.y * 32;

    // ---------- Phase A: v_posed GEMM into VP (no LDS staging) ----------
    float vtl[3];
    #pragma unroll
    for (int nt = 0; nt < 3; ++nt) {
        const int nc = c0 + wave * 48 + nt * 16 + col;
        vtl[nt] = (nc < NUM_COORDS) ? vt[nc] : 0.f;
    }

    f32x4 acc[2][3] = {{{0.f,0.f,0.f,0.f},{0.f,0.f,0.f,0.f},{0.f,0.f,0.f,0.f}},
                       {{0.f,0.f,0.f,0.f},{0.f,0.f,0.f,0.f},{0.f,0.f,0.f,0.f}}};
    #pragma unroll
    for (int kb = 0; kb < 7; ++kb) {
        short8 b3[3];
        #pragma unroll
        for (int nt = 0; nt < 3; ++nt) {
            const int nc = c0 + wave * 48 + nt * 16 + col;
            b3[nt] = *(const short8*)(dbf + (size_t)nc * KPAD + quad * 8 + kb * 32);
        }
        short8 a2[2];
        #pragma unroll
        for (int mt = 0; mt < 2; ++mt)
            a2[mt] = *(const short8*)(xbf + (size_t)(b0 + mt * 16 + col) * KPAD + quad * 8 + kb * 32);
        #pragma unroll
        for (int mt = 0; mt < 2; ++mt)
            #pragma unroll
            for (int nt = 0; nt < 3; ++nt)
                acc[mt][nt] = __builtin_amdgcn_mfma_f32_16x16x32_bf16(a2[mt], b3[nt], acc[mt][nt], 0, 0, 0);
    }
    #pragma unroll
    for (int mt = 0; mt < 2; ++mt)
        #pragma unroll
        for (int nt = 0; nt < 3; ++nt) {
            const int cc = wave * 48 + nt * 16 + col;
            #pragma unroll
            for (int r = 0; r < 4; ++r)
                VP[(mt * 16 + quad * 4 + r) * 194 + cc] = acc[mt][nt][r] + vtl[nt];
        }
    __syncthreads();   // the ONLY block-wide barrier

    // ---------- Phase B: skinning from VP, half-Ts ----------
    const int v0 = blockIdx.x * 64;
    short8 wfrag[4];
    #pragma unroll
    for (int mt = 0; mt < 4; ++mt)
        wfrag[mt] = *(const short8*)(whbf + (size_t)(v0 + mt * 16 + col) * 32 + quad * 8);

    float* ts = &Tsf[wave][0];
    const int vv = v0 + lane;
    const bool vok = (vv < NUM_VERTS);
    const int lhalf = lane & 31;

    for (int nt = wave; nt < 32; nt += 4) {
        const int b = b0 + nt;
        const short8 bh = *(const short8*)(ahi + ((size_t)b * 16 + col) * 32 + quad * 8);
        const short8 bl = *(const short8*)(alo + ((size_t)b * 16 + col) * 32 + quad * 8);

        f32x4 acc2[4];
        #pragma unroll
        for (int mt = 0; mt < 4; ++mt) {
            f32x4 z = {0.f, 0.f, 0.f, 0.f};
            z = __builtin_amdgcn_mfma_f32_16x16x32_bf16(wfrag[mt], bh, z, 0, 0, 0);
            z = __builtin_amdgcn_mfma_f32_16x16x32_bf16(wfrag[mt], bl, z, 0, 0, 0);
            acc2[mt] = z;
        }

        const float h0 = VP[nt * 194 + lane * 3 + 0];
        const float h1 = VP[nt * 194 + lane * 3 + 1];
        const float h2 = VP[nt * 194 + lane * 3 + 2];
        float* orow = out + (size_t)b * NUM_COORDS + (size_t)vv * 3;

        // half 0: verts 0-31 (mt 0,1). All lanes write; lanes <32 read+store.
        #pragma unroll
        for (int mt = 0; mt < 2; ++mt)
            #pragma unroll
            for (int r = 0; r < 4; ++r)
                ts[(mt * 16 + quad * 4 + r) * 20 + col] = acc2[mt][r];
        if (lane < 32) {
            const f32x4 t0 = *(const f32x4*)(ts + lhalf * 20 + 0);
            const f32x4 t1 = *(const f32x4*)(ts + lhalf * 20 + 4);
            const f32x4 t2 = *(const f32x4*)(ts + lhalf * 20 + 8);
            if (vok) {
                __builtin_nontemporal_store(t0[0] * h0 + t0[1] * h1 + t0[2] * h2 + t0[3], orow + 0);
                __builtin_nontemporal_store(t1[0] * h0 + t1[1] * h1 + t1[2] * h2 + t1[3], orow + 1);
                __builtin_nontemporal_store(t2[0] * h0 + t2[1] * h1 + t2[2] * h2 + t2[3], orow + 2);
            }
        }
        // half 1: verts 32-63 (mt 2,3). Same-wave DS ordering keeps this safe.
        #pragma unroll
        for (int mt = 2; mt < 4; ++mt)
            #pragma unroll
            for (int r = 0; r < 4; ++r)
                ts[((mt - 2) * 16 + quad * 4 + r) * 20 + col] = acc2[mt][r];
        if (lane >= 32) {
            const f32x4 t0 = *(const f32x4*)(ts + lhalf * 20 + 0);
            const f32x4 t1 = *(const f32x4*)(ts + lhalf * 20 + 4);
            const f32x4 t2 = *(const f32x4*)(ts + lhalf * 20 + 8);
            if (vok) {
                __builtin_nontemporal_store(t0[0] * h0 + t0[1] * h1 + t0[2] * h2 + t0[3], orow + 0);
                __builtin_nontemporal_store(t1[0] * h0 + t1[1] * h1 + t1[2] * h2 + t1[3], orow + 1);
                __builtin_nontemporal_store(t2[0] * h0 + t2[1] * h1 + t2[2] * h2 + t2[3], orow + 2);
            }
        }
    }
}

extern "C" void kernel_launch(void* const* d_in, const int* in_sizes, int n_in,
                              void* d_out, int out_size, void* d_ws, size_t ws_size,
                              hipStream_t stream) {
    const float* x  = (const float*)d_in[0];
    const float* vt = (const float*)d_in[1];
    const float* sd = (const float*)d_in[2];
    const float* Jr = (const float*)d_in[3];
    const float* pd = (const float*)d_in[4];
    const float* w  = (const float*)d_in[5];
    float* out = (float*)d_out;
    float* ws  = (float*)d_ws;

    k_prep <<<507, 256, 0, stream>>>(Jr, sd, pd, vt, w, x, ws);
    k_pb   <<<128, 256, 0, stream>>>(x, ws);
    k_fused<<<dim3(108, 16), 256, 0, stream>>>(vt, out, ws);
}

// Round 11
// 141.679 us; speedup vs baseline: 1.0390x; 1.0390x over previous
//
#include <hip/hip_runtime.h>

#define NUM_JOINTS 24
#define NUM_VERTS  6890
#define NUM_COORDS (NUM_VERTS * 3)   // 20670
#define NUM_BETAS  10
#define KTOT       217               // 10 betas + 207 pose features
#define KPAD       224               // padded K for MFMA (7 x 32)
#define BATCH      512
#define VPAD       6912              // padded vertex count

// ---- ws layout (float offsets); ushort regions: floats = ushorts/2 ----
#define WS_SJP  0          //  85536: float 108 strips x 792 partials (strip0 = reduced)
#define WS_XBF  85536      //  57344: ushort 512 x 224
#define WS_DBF  142880     // 2322432: ushort 20736 x 224
#define WS_WHBF 2465312    // 110592: ushort 6912 x 32
#define WS_AH   2575904    // 131072: ushort 8192 x 32
#define WS_AL   2706976    // 131072: ushort 8192 x 32
#define WS_RS   2838048    // 110592: float Rs[512][24][9]  -> total ~11.8 MB

typedef __attribute__((ext_vector_type(8))) short short8;
typedef __attribute__((ext_vector_type(4))) float f32x4;

__device__ inline unsigned short f2bf(float f) {
    union { float f; unsigned u; } c; c.f = f;
    unsigned u = c.u;
    u += 0x7fffu + ((u >> 16) & 1u);   // RNE
    return (unsigned short)(u >> 16);
}
__device__ inline float bf2f(unsigned short h) {
    union { unsigned u; float f; } c; c.u = ((unsigned)h) << 16;
    return c.f;
}

struct PBShm {
    float Rs[4][24][9];
    float Jl[4][24][3];
    float Rg[4][24][9];
    float tg[4][24][3];
    float As[4][24][12];
};   // 13824 B

// ================= k_prep (r11 = r10-verified): 507 blocks =================
// strips write plain partials; rodrigues + xbf in tail blocks (t 459..506).
__global__ __launch_bounds__(256) void k_prep(const float* __restrict__ Jr,
                                              const float* __restrict__ sd,
                                              const float* __restrict__ pd,
                                              const float* __restrict__ vt,
                                              const float* __restrict__ w,
                                              const float* __restrict__ x,
                                              float* __restrict__ ws) {
    __shared__ __align__(16) unsigned char smem[28928];
    const int t   = blockIdx.x;
    const int tid = threadIdx.x;
    unsigned short* whbf = (unsigned short*)(ws + WS_WHBF);
    unsigned short* dbf  = (unsigned short*)(ws + WS_DBF);
    unsigned short* xbf  = (unsigned short*)(ws + WS_XBF);

    if (t < 27) {
        const int v = t * 256 + tid;      // < 6912
        const bool ok = (v < NUM_VERTS);
        unsigned short row[32];
        #pragma unroll
        for (int j = 0; j < 32; ++j)
            row[j] = f2bf((ok && j < 24) ? w[v * 24 + j] : 0.f);
        #pragma unroll
        for (int i = 0; i < 4; ++i)
            *(float4*)(whbf + (size_t)v * 32 + i * 8) = *(const float4*)(&row[i * 8]);
    } else if (t < 351) {
        unsigned* L = (unsigned*)smem;        // [64][113] dwords
        const int c0   = (t - 27) * 64;
        const int lane = tid & 63;
        const int grp  = tid >> 6;
        const int c    = c0 + lane;
        const bool cv  = (c < NUM_COORDS);
        #pragma unroll 4
        for (int i = 0; i < 28; ++i) {
            const int p  = i * 4 + grp;
            const int k0 = 2 * p, k1 = k0 + 1;
            float v0 = 0.f, v1 = 0.f;
            if (cv) {
                v0 = (k0 < 10) ? sd[(size_t)k0 * NUM_COORDS + c]
                   : (k0 < KTOT) ? pd[(size_t)(k0 - 10) * NUM_COORDS + c] : 0.f;
                v1 = (k1 < 10) ? sd[(size_t)k1 * NUM_COORDS + c]
                   : (k1 < KTOT) ? pd[(size_t)(k1 - 10) * NUM_COORDS + c] : 0.f;
            }
            L[lane * 113 + p] = (unsigned)f2bf(v0) | ((unsigned)f2bf(v1) << 16);
        }
        __syncthreads();
        #pragma unroll
        for (int i = 0; i < 7; ++i) {
            const int idx = i * 256 + tid;
            const int row = idx / 28;
            const int q   = idx % 28;
            uint4 val;
            val.x = L[row * 113 + q * 4 + 0];
            val.y = L[row * 113 + q * 4 + 1];
            val.z = L[row * 113 + q * 4 + 2];
            val.w = L[row * 113 + q * 4 + 3];
            *(uint4*)(dbf + (size_t)(c0 + row) * KPAD + q * 8) = val;
        }
    } else if (t < 459) {
        float* Jl = (float*)smem;
        float* S  = (float*)smem + 64 * 25;
        const int strip = t - 351;
        const int v0 = strip * 64;
        #pragma unroll
        for (int i = 0; i < 6; ++i) {
            const int idx = i * 256 + tid;
            const int v = idx / 24, j = idx % 24;
            Jl[v * 25 + j] = (v0 + v < NUM_VERTS) ? Jr[(size_t)(v0 + v) * 24 + j] : 0.f;
        }
        #pragma unroll
        for (int i = 0; i < 9; ++i) {
            const int idx = i * 256 + tid;
            if (idx < 33 * 64) {
                const int s = idx / 64, v = idx % 64;
                float val = 0.f;
                if (v0 + v < NUM_VERTS) {
                    if (s < 30) val = sd[(size_t)(s / 3) * NUM_COORDS + (size_t)(v0 + v) * 3 + (s % 3)];
                    else        val = vt[(size_t)(v0 + v) * 3 + (s - 30)];
                }
                S[s * 64 + v] = val;
            }
        }
        __syncthreads();
        float* wsp = ws + WS_SJP + (size_t)strip * 792;
        for (int o = tid; o < 792; o += 256) {
            const int s = o / 24, j = o % 24;
            float sum = 0.f;
            #pragma unroll 8
            for (int v = 0; v < 64; ++v)
                sum += S[s * 64 + v] * Jl[v * 25 + j];
            wsp[o] = sum;
        }
    } else {
        // rodrigues + xbf: thread = one (b, j) pair (r9-verified)
        const int idx = (t - 459) * 256 + tid;   // < 12288
        const int b = idx / 24;
        const int j = idx % 24;
        const float* row = x + b * (NUM_BETAS + 72);
        const float t0 = row[3 * j + 0], t1 = row[3 * j + 1], t2 = row[3 * j + 2];
        const float a0 = t0 + 1e-8f, a1 = t1 + 1e-8f, a2 = t2 + 1e-8f;
        const float angle = sqrtf(a0 * a0 + a1 * a1 + a2 * a2);
        const float inv = 1.0f / angle;
        const float rx = t0 * inv, ry = t1 * inv, rz = t2 * inv;
        const float c = cosf(angle), sn = sinf(angle), o = 1.f - c;
        float R[9];
        R[0] = c + o * rx * rx;       R[1] = o * rx * ry - sn * rz; R[2] = o * rx * rz + sn * ry;
        R[3] = o * rx * ry + sn * rz; R[4] = c + o * ry * ry;       R[5] = o * ry * rz - sn * rx;
        R[6] = o * rx * rz - sn * ry; R[7] = o * ry * rz + sn * rx; R[8] = c + o * rz * rz;
        float* rsd = ws + WS_RS + (size_t)(b * 24 + j) * 9;
        #pragma unroll
        for (int i = 0; i < 9; ++i) rsd[i] = R[i];
        if (j >= 1) {
            #pragma unroll
            for (int i = 0; i < 9; ++i) {
                const float pf = R[i] - ((i == 0 || i == 4 || i == 8) ? 1.f : 0.f);
                xbf[(size_t)b * KPAD + 10 + (j - 1) * 9 + i] = f2bf(pf);
            }
        } else {
            #pragma unroll
            for (int k = 0; k < NUM_BETAS; ++k)
                xbf[(size_t)b * KPAD + k] = f2bf(row[72 + k]);
            #pragma unroll
            for (int k = KTOT; k < KPAD; ++k)
                xbf[(size_t)b * KPAD + k] = 0;
        }
    }
}

// ================= k_red (r8-verified): collapse 108 SJ strips once =================
__global__ __launch_bounds__(256) void k_red(float* __restrict__ ws) {
    const int o = blockIdx.x * 256 + threadIdx.x;
    if (o >= 792) return;
    const float* wsp = ws + WS_SJP;
    float s0 = 0.f, s1 = 0.f, s2 = 0.f, s3 = 0.f;
    #pragma unroll
    for (int s = 0; s < 108; s += 4) {
        s0 += wsp[(size_t)(s + 0) * 792 + o];
        s1 += wsp[(size_t)(s + 1) * 792 + o];
        s2 += wsp[(size_t)(s + 2) * 792 + o];
        s3 += wsp[(size_t)(s + 3) * 792 + o];
    }
    ws[WS_SJP + o] = (s0 + s1) + (s2 + s3);
}

// ================= k_pb (r11 = pb-lite + parallel chain): 128 blocks =================
__global__ __launch_bounds__(256) void k_pb(const float* __restrict__ x,
                                            float* __restrict__ ws) {
    __shared__ PBShm P;
    __shared__ float SJf[792];
    unsigned short* ahi = (unsigned short*)(ws + WS_AH);
    unsigned short* alo = (unsigned short*)(ws + WS_AL);
    const int tid = threadIdx.x;

    for (int o = tid; o < 792; o += 256)
        SJf[o] = ws[WS_SJP + o];
    __syncthreads();

    const int sub  = tid >> 6;
    const int lane = tid & 63;
    const int b = blockIdx.x * 4 + sub;
    const float* row = x + b * (NUM_BETAS + 72);

    if (lane < 24) {
        const int j = lane;
        const float* rsd = ws + WS_RS + (size_t)(b * 24 + j) * 9;
        #pragma unroll
        for (int i = 0; i < 9; ++i) P.Rs[sub][j][i] = rsd[i];
        #pragma unroll
        for (int c3 = 0; c3 < 3; ++c3) {
            float s = SJf[(30 + c3) * 24 + j];
            #pragma unroll
            for (int k = 0; k < NUM_BETAS; ++k)
                s += row[72 + k] * SJf[(k * 3 + c3) * 24 + j];
            P.Jl[sub][j][c3] = s;
        }
    }
    __syncthreads();

    // ---- parallel kinematic chain: lane j = joint j, tree levels (r8-verified) ----
    {
        constexpr int PAR[24] = {0, 0, 0, 0, 1, 2, 3, 4, 5, 6, 7, 8,
                                 9, 9, 9, 12, 13, 14, 16, 17, 18, 19, 20, 21};
        int p = 0;
        #pragma unroll
        for (int q = 1; q < 24; ++q) if (lane == q) p = PAR[q];

        if (lane == 0) {
            #pragma unroll
            for (int q = 0; q < 9; ++q) P.Rg[sub][0][q] = P.Rs[sub][0][q];
            #pragma unroll
            for (int c3 = 0; c3 < 3; ++c3) P.tg[sub][0][c3] = P.Jl[sub][0][c3];
        }
        __syncthreads();

        #pragma unroll
        for (int lvl = 1; lvl <= 8; ++lvl) {
            constexpr unsigned LVL[9] = {0x000001u, 0x00000Eu, 0x000070u,
                                         0x000380u, 0x007C00u, 0x038000u,
                                         0x0C0000u, 0x300000u, 0xC00000u};
            if (lane < 24 && ((LVL[lvl] >> lane) & 1u)) {
                const int j = lane;
                float Rp[9], Rsl[9], tp[3];
                #pragma unroll
                for (int q = 0; q < 9; ++q) { Rp[q] = P.Rg[sub][p][q]; Rsl[q] = P.Rs[sub][j][q]; }
                #pragma unroll
                for (int r = 0; r < 3; ++r) tp[r] = P.tg[sub][p][r];
                float tmp[9];
                #pragma unroll
                for (int r = 0; r < 3; ++r)
                    #pragma unroll
                    for (int cc = 0; cc < 3; ++cc)
                        tmp[r * 3 + cc] = Rp[r * 3 + 0] * Rsl[0 + cc] +
                                          Rp[r * 3 + 1] * Rsl[3 + cc] +
                                          Rp[r * 3 + 2] * Rsl[6 + cc];
                #pragma unroll
                for (int q = 0; q < 9; ++q) P.Rg[sub][j][q] = tmp[q];
                const float tr0 = P.Jl[sub][j][0] - P.Jl[sub][p][0];
                const float tr1 = P.Jl[sub][j][1] - P.Jl[sub][p][1];
                const float tr2 = P.Jl[sub][j][2] - P.Jl[sub][p][2];
                #pragma unroll
                for (int r = 0; r < 3; ++r)
                    P.tg[sub][j][r] = Rp[r * 3 + 0] * tr0 + Rp[r * 3 + 1] * tr1 +
                                      Rp[r * 3 + 2] * tr2 + tp[r];
            }
            __syncthreads();
        }
    }

    if (lane < 24) {
        const int j = lane;
        #pragma unroll
        for (int r = 0; r < 3; ++r) {
            const float tt = P.tg[sub][j][r] - (P.Rg[sub][j][r * 3 + 0] * P.Jl[sub][j][0] +
                                                P.Rg[sub][j][r * 3 + 1] * P.Jl[sub][j][1] +
                                                P.Rg[sub][j][r * 3 + 2] * P.Jl[sub][j][2]);
            P.As[sub][j][r * 4 + 0] = P.Rg[sub][j][r * 3 + 0];
            P.As[sub][j][r * 4 + 1] = P.Rg[sub][j][r * 3 + 1];
            P.As[sub][j][r * 4 + 2] = P.Rg[sub][j][r * 3 + 2];
            P.As[sub][j][r * 4 + 3] = tt;
        }
    }
    __syncthreads();

    if (lane < 32) {
        const int r = lane >> 1;
        const int half = lane & 1;
        unsigned short hi[16], lo[16];
        #pragma unroll
        for (int i = 0; i < 16; ++i) {
            const int j = half * 16 + i;
            float v = 0.f;
            if (r < 12 && j < 24) v = P.As[sub][j][r];
            const unsigned short h = f2bf(v);
            hi[i] = h;
            lo[i] = f2bf(v - bf2f(h));
        }
        unsigned short* dh = ahi + ((size_t)b * 16 + r) * 32 + half * 16;
        unsigned short* dl = alo + ((size_t)b * 16 + r) * 32 + half * 16;
        #pragma unroll
        for (int i = 0; i < 2; ++i) {
            *(float4*)(dh + i * 8) = *(const float4*)(&hi[i * 8]);
            *(float4*)(dl + i * 8) = *(const float4*)(&lo[i * 8]);
        }
    }
}

// ================= k_fused (r6/r8-verified): grid (108, 16), 4 blocks/CU =================
__global__ __launch_bounds__(256, 4) void k_fused(const float* __restrict__ vt,
                                                  float* __restrict__ out,
                                                  float* __restrict__ ws) {
    __shared__ __align__(16) float VP[32 * 194];     // 24832 B: v_posed[bb][cc]
    __shared__ __align__(16) float Tsf[4][32 * 20];  // 10240 B: half-T per wave

    const unsigned short* dbf  = (const unsigned short*)(ws + WS_DBF);
    const unsigned short* xbf  = (const unsigned short*)(ws + WS_XBF);
    const unsigned short* whbf = (const unsigned short*)(ws + WS_WHBF);
    const unsigned short* ahi  = (const unsigned short*)(ws + WS_AH);
    const unsigned short* alo  = (const unsigned short*)(ws + WS_AL);

    const int tid  = threadIdx.x;
    const int wave = tid >> 6;
    const int lane = tid & 63;
    const int col  = lane & 15;
    const int quad = lane >> 4;
    const int c0   = blockIdx.x * 192;
    const int b0   = blockIdx.y * 32;

    // ---------- Phase A: v_posed GEMM into VP (no LDS staging) ----------
    float vtl[3];
    #pragma unroll
    for (int nt = 0; nt < 3; ++nt) {
        const int nc = c0 + wave * 48 + nt * 16 + col;
        vtl[nt] = (nc < NUM_COORDS) ? vt[nc] : 0.f;
    }

    f32x4 acc[2][3] = {{{0.f,0.f,0.f,0.f},{0.f,0.f,0.f,0.f},{0.f,0.f,0.f,0.f}},
                       {{0.f,0.f,0.f,0.f},{0.f,0.f,0.f,0.f},{0.f,0.f,0.f,0.f}}};
    #pragma unroll
    for (int kb = 0; kb < 7; ++kb) {
        short8 b3[3];
        #pragma unroll
        for (int nt = 0; nt < 3; ++nt) {
            const int nc = c0 + wave * 48 + nt * 16 + col;
            b3[nt] = *(const short8*)(dbf + (size_t)nc * KPAD + quad * 8 + kb * 32);
        }
        short8 a2[2];
        #pragma unroll
        for (int mt = 0; mt < 2; ++mt)
            a2[mt] = *(const short8*)(xbf + (size_t)(b0 + mt * 16 + col) * KPAD + quad * 8 + kb * 32);
        #pragma unroll
        for (int mt = 0; mt < 2; ++mt)
            #pragma unroll
            for (int nt = 0; nt < 3; ++nt)
                acc[mt][nt] = __builtin_amdgcn_mfma_f32_16x16x32_bf16(a2[mt], b3[nt], acc[mt][nt], 0, 0, 0);
    }
    #pragma unroll
    for (int mt = 0; mt < 2; ++mt)
        #pragma unroll
        for (int nt = 0; nt < 3; ++nt) {
            const int cc = wave * 48 + nt * 16 + col;
            #pragma unroll
            for (int r = 0; r < 4; ++r)
                VP[(mt * 16 + quad * 4 + r) * 194 + cc] = acc[mt][nt][r] + vtl[nt];
        }
    __syncthreads();   // the ONLY block-wide barrier

    // ---------- Phase B: skinning from VP, half-Ts ----------
    const int v0 = blockIdx.x * 64;
    short8 wfrag[4];
    #pragma unroll
    for (int mt = 0; mt < 4; ++mt)
        wfrag[mt] = *(const short8*)(whbf + (size_t)(v0 + mt * 16 + col) * 32 + quad * 8);

    float* ts = &Tsf[wave][0];
    const int vv = v0 + lane;
    const bool vok = (vv < NUM_VERTS);
    const int lhalf = lane & 31;

    for (int nt = wave; nt < 32; nt += 4) {
        const int b = b0 + nt;
        const short8 bh = *(const short8*)(ahi + ((size_t)b * 16 + col) * 32 + quad * 8);
        const short8 bl = *(const short8*)(alo + ((size_t)b * 16 + col) * 32 + quad * 8);

        f32x4 acc2[4];
        #pragma unroll
        for (int mt = 0; mt < 4; ++mt) {
            f32x4 z = {0.f, 0.f, 0.f, 0.f};
            z = __builtin_amdgcn_mfma_f32_16x16x32_bf16(wfrag[mt], bh, z, 0, 0, 0);
            z = __builtin_amdgcn_mfma_f32_16x16x32_bf16(wfrag[mt], bl, z, 0, 0, 0);
            acc2[mt] = z;
        }

        const float h0 = VP[nt * 194 + lane * 3 + 0];
        const float h1 = VP[nt * 194 + lane * 3 + 1];
        const float h2 = VP[nt * 194 + lane * 3 + 2];
        float* orow = out + (size_t)b * NUM_COORDS + (size_t)vv * 3;

        // half 0: verts 0-31 (mt 0,1). All lanes write; lanes <32 read+store.
        #pragma unroll
        for (int mt = 0; mt < 2; ++mt)
            #pragma unroll
            for (int r = 0; r < 4; ++r)
                ts[(mt * 16 + quad * 4 + r) * 20 + col] = acc2[mt][r];
        if (lane < 32) {
            const f32x4 t0 = *(const f32x4*)(ts + lhalf * 20 + 0);
            const f32x4 t1 = *(const f32x4*)(ts + lhalf * 20 + 4);
            const f32x4 t2 = *(const f32x4*)(ts + lhalf * 20 + 8);
            if (vok) {
                __builtin_nontemporal_store(t0[0] * h0 + t0[1] * h1 + t0[2] * h2 + t0[3], orow + 0);
                __builtin_nontemporal_store(t1[0] * h0 + t1[1] * h1 + t1[2] * h2 + t1[3], orow + 1);
                __builtin_nontemporal_store(t2[0] * h0 + t2[1] * h1 + t2[2] * h2 + t2[3], orow + 2);
            }
        }
        // half 1: verts 32-63 (mt 2,3). Same-wave DS ordering keeps this safe.
        #pragma unroll
        for (int mt = 2; mt < 4; ++mt)
            #pragma unroll
            for (int r = 0; r < 4; ++r)
                ts[((mt - 2) * 16 + quad * 4 + r) * 20 + col] = acc2[mt][r];
        if (lane >= 32) {
            const f32x4 t0 = *(const f32x4*)(ts + lhalf * 20 + 0);
            const f32x4 t1 = *(const f32x4*)(ts + lhalf * 20 + 4);
            const f32x4 t2 = *(const f32x4*)(ts + lhalf * 20 + 8);
            if (vok) {
                __builtin_nontemporal_store(t0[0] * h0 + t0[1] * h1 + t0[2] * h2 + t0[3], orow + 0);
                __builtin_nontemporal_store(t1[0] * h0 + t1[1] * h1 + t1[2] * h2 + t1[3], orow + 1);
                __builtin_nontemporal_store(t2[0] * h0 + t2[1] * h1 + t2[2] * h2 + t2[3], orow + 2);
            }
        }
    }
}

extern "C" void kernel_launch(void* const* d_in, const int* in_sizes, int n_in,
                              void* d_out, int out_size, void* d_ws, size_t ws_size,
                              hipStream_t stream) {
    const float* x  = (const float*)d_in[0];
    const float* vt = (const float*)d_in[1];
    const float* sd = (const float*)d_in[2];
    const float* Jr = (const float*)d_in[3];
    const float* pd = (const float*)d_in[4];
    const float* w  = (const float*)d_in[5];
    float* out = (float*)d_out;
    float* ws  = (float*)d_ws;

    k_prep <<<507, 256, 0, stream>>>(Jr, sd, pd, vt, w, x, ws);
    k_red  <<<4,   256, 0, stream>>>(ws);
    k_pb   <<<128, 256, 0, stream>>>(x, ws);
    k_fused<<<dim3(108, 16), 256, 0, stream>>>(vt, out, ws);
}